// Round 13
// baseline (33.325 us; speedup 1.0000x reference)
//
#include <hip/hip_runtime.h>
#include <math.h>

#define APAD 28          // padded row stride for 21-wide tiles
#define W1PAD 132        // padded row stride for 128-wide tiles

// ws float layout (acc zeroed by block 44 each launch; poison-safe):
#define WS_ACC1 0
#define WS_ACC2 512
#define WS_ACC3 1024

// Reset-based dataflow sync: all words 0 at module load; finalizer restores
// them to 0 before kernel end (end-of-dispatch release + stream ordering
// publish the resets to the next launch / graph replay).
__device__ unsigned g_zr;    // accumulators zeroed (set by block 44)
__device__ unsigned g_d1;    // FC1 producers done (target 21)
__device__ unsigned g_d2;    // FC2 producers done (target 16)
__device__ unsigned g_cnt;   // FC3 producers done (target 8; 8th finalizes)

// Agent-scope relaxed atomics: cache-bypassing ops served at the coherence
// point -> no L2 wb/inv fences needed anywhere. A vmcnt(0) drain (the
// __syncthreads lowering) means RMWs/stores are acked at the coherence point
// = globally visible; counter bumps after the drain publish the stage.
__device__ __forceinline__ float agent_load(const float* p) {
    return __hip_atomic_load(p, __ATOMIC_RELAXED, __HIP_MEMORY_SCOPE_AGENT);
}
__device__ __forceinline__ void agent_store(float* p, float v) {
    __hip_atomic_store(p, v, __ATOMIC_RELAXED, __HIP_MEMORY_SCOPE_AGENT);
}
__device__ __forceinline__ unsigned flag_load(const unsigned* p) {
    return __hip_atomic_load(p, __ATOMIC_RELAXED, __HIP_MEMORY_SCOPE_AGENT);
}
__device__ __forceinline__ void flag_store(unsigned* p, unsigned v) {
    __hip_atomic_store(p, v, __ATOMIC_RELAXED, __HIP_MEMORY_SCOPE_AGENT);
}
__device__ __forceinline__ void flag_bump(unsigned* p, unsigned* out_prev) {
    *out_prev = __hip_atomic_fetch_add(p, 1u, __ATOMIC_RELAXED,
                                       __HIP_MEMORY_SCOPE_AGENT);
}
__device__ __forceinline__ float agent_fadd(float* p, float v) {
    return __hip_atomic_fetch_add(p, v, __ATOMIC_RELAXED, __HIP_MEMORY_SCOPE_AGENT);
}

// Block barrier waiting ONLY on LDS ops (lgkmcnt): global prefetch loads
// stay in flight across it (__syncthreads would drain vmcnt(0)).
__device__ __forceinline__ void lds_barrier() {
    asm volatile("s_waitcnt lgkmcnt(0)\n\ts_barrier" ::: "memory");
}

// Single launch, 45 blocks x 512 threads, pure dataflow pipeline:
//   blocks 0-20 : GCN (P0-P4 full, P5 row b) + FC1 rows [21b,+21) -> g_d1++
//   blocks 21-36: poll g_d1==21 -> FC2 rows [32(b-21),+32)        -> g_d2++
//   blocks 37-44: poll g_d2==16 -> FC3 rows [64(b-37),+64)        -> g_cnt++
// GCN GEMM phases (P1/P3/P4) use 2x2 REGISTER TILING: 121 threads (11x11
// tiles) read 2 rows of each operand for 4 outputs -> LDS wave-instr count
// drops 616 -> 352 (DS pipe was the GCN bottleneck at ~12cy/ds_read_b128).
// Per-output accumulation order is unchanged (bit-identical results).
__global__ __launch_bounds__(512) void fused_kernel(
    const float* __restrict__ state,      // [B,21,128], only batch 0 used
    const int*   __restrict__ edge_index, // [2,128]
    const float* __restrict__ W1,         // [128,21]
    const float* __restrict__ b1,         // [21]
    const float* __restrict__ W2,         // [21,21]
    const float* __restrict__ b2,         // [21]
    const float* __restrict__ Wf1,        // [441,512]
    const float* __restrict__ bf1,        // [512]
    const float* __restrict__ Wf2,        // [512,512]
    const float* __restrict__ bf2,        // [512]
    const float* __restrict__ Wf3,        // [512,256]
    const float* __restrict__ bf3,        // [256]
    float* __restrict__ ws,
    float* __restrict__ out)
{
    const int b = blockIdx.x;
    const int t = threadIdx.x;

    // ================= FC3 role (blocks 37..44) =================
    if (b >= 37) {
        if (b == 44) {
            agent_store(&ws[WS_ACC1 + t], 0.0f);
            agent_store(&ws[WS_ACC2 + t], 0.0f);
            if (t < 256) agent_store(&ws[WS_ACC3 + t], 0.0f);
            __syncthreads();                      // drain zeros (vmcnt 0)
            if (t == 0) flag_store(&g_zr, 1u);
        }

        const int r0 = 64 * (b - 37);
        float wf3v[64];
        if (t < 256) {
            #pragma unroll
            for (int i = 0; i < 64; ++i)
                wf3v[i] = Wf3[(size_t)(r0 + i) * 256 + t];
        }
        const float rbf2 = (t < 64) ? bf2[r0 + t] : 0.0f;
        const float rbf3 = bf3[t & 255];

        __shared__ float x2s[64];
        __shared__ unsigned sflag;

        if (t == 0) {
            while (flag_load(&g_d2) < 16u) __builtin_amdgcn_s_sleep(1);
        }
        __syncthreads();

        if (t < 64)
            x2s[t] = fmaxf(agent_load(&ws[WS_ACC2 + r0 + t]) + rbf2, 0.0f);
        lds_barrier();
        if (t < 256) {
            float s = 0.0f;
            #pragma unroll
            for (int j = 0; j < 64; ++j) s += x2s[j] * wf3v[j];
            agent_fadd(&ws[WS_ACC3 + t], s);
        }

        __syncthreads();                          // drain FC3 adds
        if (t == 0) {
            unsigned prev; flag_bump(&g_cnt, &prev);
            sflag = (prev == 7u) ? 1u : 0u;
        }
        __syncthreads();
        if (sflag) {
            if (t < 256) {
                float a = agent_load(&ws[WS_ACC3 + t]) + rbf3;
                out[t] = fmaxf(a, 0.0f);
            }
            if (t == 256) flag_store(&g_zr, 0u);
            if (t == 257) flag_store(&g_d1, 0u);
            if (t == 258) flag_store(&g_d2, 0u);
            if (t == 259) flag_store(&g_cnt, 0u);
        }
        return;
    }

    // ================= FC2 role (blocks 21..36) =================
    if (b >= 21) {
        const int r0 = 32 * (b - 21);
        float wf2v[32];
        #pragma unroll
        for (int i = 0; i < 32; ++i)
            wf2v[i] = Wf2[(size_t)(r0 + i) * 512 + t];
        const float rbf1 = (t < 32) ? bf1[r0 + t] : 0.0f;

        __shared__ float x1s[32];

        if (t == 0) {
            while (flag_load(&g_d1) < 21u) __builtin_amdgcn_s_sleep(1);
        }
        __syncthreads();

        if (t < 32)
            x1s[t] = fmaxf(agent_load(&ws[WS_ACC1 + r0 + t]) + rbf1, 0.0f);
        lds_barrier();
        {
            float s = 0.0f;
            #pragma unroll
            for (int j = 0; j < 32; ++j) s += x1s[j] * wf2v[j];
            agent_fadd(&ws[WS_ACC2 + t], s);
        }

        __syncthreads();                          // drain FC2 adds
        if (t == 0) { unsigned prev; flag_bump(&g_d2, &prev); }
        return;
    }

    // ================= GCN + FC1 role (blocks 0..20) =================
    __shared__ float sA[21 * APAD];
    __shared__ float sX[21 * W1PAD];
    __shared__ float sW1T[21 * W1PAD];
    __shared__ float sW2T[21 * APAD];
    __shared__ float sT[21 * APAD];      // h1T then h2T
    __shared__ float sG[21 * APAD];      // g1
    __shared__ float sv[21];             // v row b
    __shared__ float sdeg[21];
    __shared__ float sb1[21], sb2[21];

    // 2x2 tile coordinates for the GEMM phases (121 threads active):
    const int ti = t / 11, tj = t - 11 * (t / 11);   // valid when t < 121
    const int n0 = 2 * ti, k0 = 2 * tj;
    const bool tile_act = (t < 121);
    const bool hasN1 = (n0 + 1 < 21), hasK1 = (k0 + 1 < 21);
    const int n1 = hasN1 ? n0 + 1 : n0;
    const int k1 = hasK1 ? k0 + 1 : k0;

    // P0: zero pads, stage X/W1T/W2T, edges (round-12 verbatim)
    for (int i = t; i < 21 * APAD; i += 512) {
        sA[i] = 0.0f; sW2T[i] = 0.0f; sT[i] = 0.0f; sG[i] = 0.0f;
    }
    if (t < 21) { sdeg[t] = 1.0f; sb1[t] = b1[t]; sb2[t] = b2[t]; }
    {
        const float4* src4 = (const float4*)state;      // batch 0
        for (int i = t; i < 672; i += 512) {            // 21*128/4
            int n = i >> 5, fc = i & 31;
            ((float4*)&sX[n * W1PAD])[fc] = src4[i];
        }
    }
    for (int i = t; i < 2688; i += 512) {               // W1 -> sW1T[k][f]
        int f = i / 21, k = i - f * 21;
        sW1T[k * W1PAD + f] = W1[i];
    }
    for (int i = t; i < 441; i += 512) {                // W2 -> sW2T[k][f]
        int f = i / 21, k = i - f * 21;
        sW2T[k * APAD + f] = W2[i];
    }
    int er = 0, ec = 0;
    if (t < 128) { er = edge_index[t]; ec = edge_index[128 + t]; }

    // Coalesced row-prefetch of FC1 weights rows [21b, 21b+21):
    float wf1v[21];
    #pragma unroll
    for (int i = 0; i < 21; ++i) wf1v[i] = Wf1[(size_t)(21 * b + i) * 512 + t];

    lds_barrier();

    // P1: adjacency scatter (+deg, +self-loop)  ||  h1 = X @ W1 (2x2 tiled)
    if (t < 128) {
        atomicAdd(&sA[er * APAD + ec], 1.0f);
        atomicAdd(&sdeg[ec], 1.0f);
    }
    if (t < 21) atomicAdd(&sA[t * APAD + t], 1.0f);
    if (tile_act) {
        const float4* x0 = (const float4*)&sX[n0 * W1PAD];
        const float4* x1 = (const float4*)&sX[n1 * W1PAD];
        const float4* w0 = (const float4*)&sW1T[k0 * W1PAD];
        const float4* w1 = (const float4*)&sW1T[k1 * W1PAD];
        float s00 = 0.0f, s01 = 0.0f, s10 = 0.0f, s11 = 0.0f;
        #pragma unroll
        for (int fc = 0; fc < 32; ++fc) {
            float4 a0 = x0[fc], a1 = x1[fc], b0 = w0[fc], b1v = w1[fc];
            s00 += a0.x * b0.x;  s00 += a0.y * b0.y;  s00 += a0.z * b0.z;  s00 += a0.w * b0.w;
            s01 += a0.x * b1v.x; s01 += a0.y * b1v.y; s01 += a0.z * b1v.z; s01 += a0.w * b1v.w;
            s10 += a1.x * b0.x;  s10 += a1.y * b0.y;  s10 += a1.z * b0.z;  s10 += a1.w * b0.w;
            s11 += a1.x * b1v.x; s11 += a1.y * b1v.y; s11 += a1.z * b1v.z; s11 += a1.w * b1v.w;
        }
        sT[k0 * APAD + n0] = s00;                       // h1T[k][n]
        if (hasK1) sT[k1 * APAD + n0] = s01;
        if (hasN1) sT[k0 * APAD + n1] = s10;
        if (hasN1 && hasK1) sT[k1 * APAD + n1] = s11;
    }
    lds_barrier();

    // P2: normalize A
    if (t < 441) {
        int r = t / 21, c = t - r * 21;
        float dr = 1.0f / sqrtf(sdeg[r]);
        float dc = 1.0f / sqrtf(sdeg[c]);
        sA[r * APAD + c] = dr * sA[r * APAD + c] * dc;
    }
    lds_barrier();

    // P3: g1[r,k] = b1[k] + A[r,:] . h1T[k,:]  (2x2 tiled; r=n0/n1, k=k0/k1)
    if (tile_act) {
        const float4* a0 = (const float4*)&sA[n0 * APAD];
        const float4* a1 = (const float4*)&sA[n1 * APAD];
        const float4* h0 = (const float4*)&sT[k0 * APAD];
        const float4* h1 = (const float4*)&sT[k1 * APAD];
        float s00 = sb1[k0], s01 = sb1[k1], s10 = sb1[k0], s11 = sb1[k1];
        #pragma unroll
        for (int jc = 0; jc < 6; ++jc) {
            float4 p0 = a0[jc], p1 = a1[jc], q0 = h0[jc], q1 = h1[jc];
            s00 += p0.x * q0.x; s00 += p0.y * q0.y; s00 += p0.z * q0.z; s00 += p0.w * q0.w;
            s01 += p0.x * q1.x; s01 += p0.y * q1.y; s01 += p0.z * q1.z; s01 += p0.w * q1.w;
            s10 += p1.x * q0.x; s10 += p1.y * q0.y; s10 += p1.z * q0.z; s10 += p1.w * q0.w;
            s11 += p1.x * q1.x; s11 += p1.y * q1.y; s11 += p1.z * q1.z; s11 += p1.w * q1.w;
        }
        sG[n0 * APAD + k0] = s00;                       // g1 row-major
        if (hasK1) sG[n0 * APAD + k1] = s01;
        if (hasN1) sG[n1 * APAD + k0] = s10;
        if (hasN1 && hasK1) sG[n1 * APAD + k1] = s11;
    }
    lds_barrier();

    // P4: h2[n,k] = g1[n,:] . W2T[k,:]  (2x2 tiled, stored transposed)
    if (tile_act) {
        const float4* g0 = (const float4*)&sG[n0 * APAD];
        const float4* g1v = (const float4*)&sG[n1 * APAD];
        const float4* w0 = (const float4*)&sW2T[k0 * APAD];
        const float4* w1 = (const float4*)&sW2T[k1 * APAD];
        float s00 = 0.0f, s01 = 0.0f, s10 = 0.0f, s11 = 0.0f;
        #pragma unroll
        for (int jc = 0; jc < 6; ++jc) {
            float4 p0 = g0[jc], p1 = g1v[jc], q0 = w0[jc], q1 = w1[jc];
            s00 += p0.x * q0.x; s00 += p0.y * q0.y; s00 += p0.z * q0.z; s00 += p0.w * q0.w;
            s01 += p0.x * q1.x; s01 += p0.y * q1.y; s01 += p0.z * q1.z; s01 += p0.w * q1.w;
            s10 += p1.x * q0.x; s10 += p1.y * q0.y; s10 += p1.z * q0.z; s10 += p1.w * q0.w;
            s11 += p1.x * q1.x; s11 += p1.y * q1.y; s11 += p1.z * q1.z; s11 += p1.w * q1.w;
        }
        sT[k0 * APAD + n0] = s00;                       // h2T[k][n]
        if (hasK1) sT[k1 * APAD + n0] = s01;
        if (hasN1) sT[k0 * APAD + n1] = s10;
        if (hasN1 && hasK1) sT[k1 * APAD + n1] = s11;
    }
    lds_barrier();

    // P5 (row b only): v[b,k] = b2[k] + A[b,:] . h2T[k,:]
    // Idle lane absorbs the g_zr gate concurrently (costs zero serial time).
    if (t < 21) {
        const int k = t;
        const float4* a4 = (const float4*)&sA[b * APAD];
        const float4* h4 = (const float4*)&sT[k * APAD];
        float s = sb2[k];
        #pragma unroll
        for (int jc = 0; jc < 6; ++jc) {
            float4 a = a4[jc], h = h4[jc];
            s += a.x * h.x; s += a.y * h.y; s += a.z * h.z; s += a.w * h.w;
        }
        sv[k] = s;
    }
    if (t == 448) {
        while (flag_load(&g_zr) == 0u) __builtin_amdgcn_s_sleep(1);
    }
    lds_barrier();   // orders sv writes AND the gate before FC1 adds

    // FC1 (row-split): rows [21b, 21b+21) -> acc1
    {
        float s = 0.0f;
        #pragma unroll
        for (int r = 0; r < 21; ++r) s += sv[r] * wf1v[r];
        agent_fadd(&ws[WS_ACC1 + t], s);
    }

    __syncthreads();                              // drain FC1 adds
    if (t == 0) { unsigned prev; flag_bump(&g_d1, &prev); }
}

extern "C" void kernel_launch(void* const* d_in, const int* in_sizes, int n_in,
                              void* d_out, int out_size, void* d_ws, size_t ws_size,
                              hipStream_t stream)
{
    const float* state      = (const float*)d_in[0];
    const int*   edge_index = (const int*)  d_in[1];
    const float* W1  = (const float*)d_in[2];
    const float* b1  = (const float*)d_in[3];
    const float* W2  = (const float*)d_in[4];
    const float* b2  = (const float*)d_in[5];
    const float* Wf1 = (const float*)d_in[6];
    const float* bf1 = (const float*)d_in[7];
    const float* Wf2 = (const float*)d_in[8];
    const float* bf2 = (const float*)d_in[9];
    const float* Wf3 = (const float*)d_in[10];
    const float* bf3 = (const float*)d_in[11];

    float* ws  = (float*)d_ws;
    float* out = (float*)d_out;

    fused_kernel<<<45, 512, 0, stream>>>(state, edge_index, W1, b1, W2, b2,
                                         Wf1, bf1, Wf2, bf2, Wf3, bf3, ws, out);
}

// Round 14
// 16.465 us; speedup vs baseline: 2.0240x; 2.0240x over previous
//
#include <hip/hip_runtime.h>
#include <math.h>

#define APAD 28          // padded row stride for 21-wide tiles
#define W1PAD 132        // padded row stride for 128-wide tiles

// ws float layout (acc zeroed by block 63 each launch; poison-safe):
#define WS_ACC1 0
#define WS_ACC2 512
#define WS_ACC3 1024

// Reset-based sync state: all words are 0 at module load, and the finalizer
// block restores every word to 0 before kernel end (stream ordering + the
// end-of-dispatch release fence make this visible to the next launch).
// -> no epoch arithmetic, no read-your-base races, graph/replay-safe.
__device__ unsigned g_arrive[64 * 16];   // 64B-strided arrival slots, phase 0/1/2
__device__ unsigned g_go;                // barrier release word
__device__ unsigned g_zr;                // accumulators-zeroed flag
__device__ unsigned g_cnt;               // finale completion counter

// Agent-scope relaxed atomics: cache-bypassing ops served at the coherence
// point -> no L2 wb/inv fences needed anywhere.
__device__ __forceinline__ float agent_load(const float* p) {
    return __hip_atomic_load(p, __ATOMIC_RELAXED, __HIP_MEMORY_SCOPE_AGENT);
}
__device__ __forceinline__ void agent_store(float* p, float v) {
    __hip_atomic_store(p, v, __ATOMIC_RELAXED, __HIP_MEMORY_SCOPE_AGENT);
}
__device__ __forceinline__ unsigned flag_load(const unsigned* p) {
    return __hip_atomic_load(p, __ATOMIC_RELAXED, __HIP_MEMORY_SCOPE_AGENT);
}
__device__ __forceinline__ void flag_store(unsigned* p, unsigned v) {
    __hip_atomic_store(p, v, __ATOMIC_RELAXED, __HIP_MEMORY_SCOPE_AGENT);
}
__device__ __forceinline__ float agent_fadd(float* p, float v) {
    return __hip_atomic_fetch_add(p, v, __ATOMIC_RELAXED, __HIP_MEMORY_SCOPE_AGENT);
}

// Block barrier waiting ONLY on LDS ops (lgkmcnt): global prefetch loads
// stay in flight across it (__syncthreads would drain vmcnt(0)).
__device__ __forceinline__ void lds_barrier() {
    asm volatile("s_waitcnt lgkmcnt(0)\n\ts_barrier" ::: "memory");
}

// Hierarchical grid barrier, phase = 1 then 2. Entry __syncthreads drains
// this block's stores/atomics (vmcnt 0) before the arrival flag.
__device__ __forceinline__ void grid_barrier(int blk, unsigned phase) {
    __syncthreads();
    if (blk == 0) {
        if (threadIdx.x > 0 && threadIdx.x < 64) {
            while (flag_load(&g_arrive[threadIdx.x * 16]) < phase)
                __builtin_amdgcn_s_sleep(1);
        }
        if (threadIdx.x == 0) flag_store(&g_go, phase);
    } else {
        if (threadIdx.x == 0) {
            flag_store(&g_arrive[blk * 16], phase);
            while (flag_load(&g_go) < phase)
                __builtin_amdgcn_s_sleep(1);
        }
    }
    __syncthreads();
}

// Single launch, 64 blocks x 512 threads, role-split:
//   blocks 0-20 : GCN (own row) + FC1 rows [21b, 21b+21)   (fan-in 21)
//   blocks 21-36: FC2 rows [32(b-21), +32)                 (fan-in 16)
//   blocks 37-44: FC3 rows [64(b-37), +64)                 (fan-in 8)
//   block 63    : zeroes acc1/acc2/acc3, sets g_zr
//   blocks 45-62: barrier participants only
// Barriers: FC1 -> bar(1) -> FC2 -> bar(2) -> FC3 -> completion-count finale.
__global__ __launch_bounds__(512) void fused_kernel(
    const float* __restrict__ state,      // [B,21,128], only batch 0 used
    const int*   __restrict__ edge_index, // [2,128]
    const float* __restrict__ W1,         // [128,21]
    const float* __restrict__ b1,         // [21]
    const float* __restrict__ W2,         // [21,21]
    const float* __restrict__ b2,         // [21]
    const float* __restrict__ Wf1,        // [441,512]
    const float* __restrict__ bf1,        // [512]
    const float* __restrict__ Wf2,        // [512,512]
    const float* __restrict__ bf2,        // [512]
    const float* __restrict__ Wf3,        // [512,256]
    const float* __restrict__ bf3,        // [256]
    float* __restrict__ ws,
    float* __restrict__ out)
{
    const int b = blockIdx.x;
    const int t = threadIdx.x;

    const bool is_gcn = (b < 21);                 // also the FC1 blocks
    const bool do_fc2 = (b >= 21 && b < 37);
    const bool do_fc3 = (b >= 37 && b < 45);

    // ---------------- LDS ----------------
    __shared__ float sA[21 * APAD];
    __shared__ float sX[21 * W1PAD];
    __shared__ float sW1T[21 * W1PAD];
    __shared__ float sW2T[21 * APAD];
    __shared__ float sT[21 * APAD];      // h1T then h2T
    __shared__ float sG[21 * APAD];      // g1
    __shared__ float sv[441];
    __shared__ float sdeg[21];
    __shared__ float sb1[21], sb2[21];
    __shared__ float x1s[32], x2s[64];
    __shared__ unsigned sflag;

    // ---------------- role prefetches (coalesced row reads) ----------------
    float wf1v[21];
    if (is_gcn) {
        #pragma unroll
        for (int i = 0; i < 21; ++i) wf1v[i] = Wf1[(size_t)(21 * b + i) * 512 + t];
    }
    float wf2v[32];
    float rbf1 = 0.0f;
    if (do_fc2) {
        #pragma unroll
        for (int i = 0; i < 32; ++i) wf2v[i] = Wf2[(size_t)(32 * (b - 21) + i) * 512 + t];
        if (t < 32) rbf1 = bf1[32 * (b - 21) + t];
    }
    float wf3v[64];
    float rbf2 = 0.0f;
    if (do_fc3) {
        if (t < 256) {
            #pragma unroll
            for (int i = 0; i < 64; ++i) wf3v[i] = Wf3[(size_t)(64 * (b - 37) + i) * 256 + t];
        }
        if (t < 64) rbf2 = bf2[64 * (b - 37) + t];
    }
    const float rbf3 = bf3[t & 255];   // any block may finalize

    // ---------------- zeroer: block 63 ----------------
    if (b == 63) {
        agent_store(&ws[WS_ACC1 + t], 0.0f);
        agent_store(&ws[WS_ACC2 + t], 0.0f);
        if (t < 256) agent_store(&ws[WS_ACC3 + t], 0.0f);
        __syncthreads();                          // drain zero stores (vmcnt 0)
        if (t == 0) flag_store(&g_zr, 1u);        // zeros globally visible
    }

    // ---------------- GCN: blocks 0..20 only ----------------
    if (is_gcn) {
        // P0: zero pads, stage X/W1T/W2T, edges
        for (int i = t; i < 21 * APAD; i += 512) {
            sA[i] = 0.0f; sW2T[i] = 0.0f; sT[i] = 0.0f; sG[i] = 0.0f;
        }
        if (t < 21) { sdeg[t] = 1.0f; sb1[t] = b1[t]; sb2[t] = b2[t]; }
        {
            const float4* src4 = (const float4*)state;      // batch 0
            for (int i = t; i < 672; i += 512) {            // 21*128/4
                int n = i >> 5, fc = i & 31;
                ((float4*)&sX[n * W1PAD])[fc] = src4[i];
            }
        }
        for (int i = t; i < 2688; i += 512) {               // W1 -> sW1T[k][f]
            int f = i / 21, k = i - f * 21;
            sW1T[k * W1PAD + f] = W1[i];
        }
        for (int i = t; i < 441; i += 512) {                // W2 -> sW2T[k][f]
            int f = i / 21, k = i - f * 21;
            sW2T[k * APAD + f] = W2[i];
        }
        int er = 0, ec = 0;
        if (t < 128) { er = edge_index[t]; ec = edge_index[128 + t]; }
        lds_barrier();

        // P1: adjacency scatter (+deg, +self-loop)  ||  h1 = X @ W1
        if (t < 128) {
            atomicAdd(&sA[er * APAD + ec], 1.0f);
            atomicAdd(&sdeg[ec], 1.0f);
        }
        if (t < 21) atomicAdd(&sA[t * APAD + t], 1.0f);
        if (t < 441) {
            int n = t / 21, k = t - n * 21;
            const float4* x4 = (const float4*)&sX[n * W1PAD];
            const float4* w4 = (const float4*)&sW1T[k * W1PAD];
            float s = 0.0f;
            #pragma unroll
            for (int fc = 0; fc < 32; ++fc) {
                float4 a = x4[fc], ww = w4[fc];
                s += a.x * ww.x; s += a.y * ww.y; s += a.z * ww.z; s += a.w * ww.w;
            }
            sT[k * APAD + n] = s;
        }
        lds_barrier();

        // P2: normalize A
        if (t < 441) {
            int r = t / 21, c = t - r * 21;
            float dr = 1.0f / sqrtf(sdeg[r]);
            float dc = 1.0f / sqrtf(sdeg[c]);
            sA[r * APAD + c] = dr * sA[r * APAD + c] * dc;
        }
        lds_barrier();

        // P3: g1[i,k] = b1[k] + A[i,:] . h1T[k,:]
        if (t < 441) {
            int r = t / 21, k = t - r * 21;
            const float4* a4 = (const float4*)&sA[r * APAD];
            const float4* h4 = (const float4*)&sT[k * APAD];
            float s = sb1[k];
            #pragma unroll
            for (int jc = 0; jc < 6; ++jc) {
                float4 a = a4[jc], h = h4[jc];
                s += a.x * h.x; s += a.y * h.y; s += a.z * h.z; s += a.w * h.w;
            }
            sG[r * APAD + k] = s;
        }
        lds_barrier();

        // P4: h2[n,k] = g1[n,:] . W2T[k,:]
        if (t < 441) {
            int n = t / 21, k = t - n * 21;
            const float4* g4 = (const float4*)&sG[n * APAD];
            const float4* w4 = (const float4*)&sW2T[k * APAD];
            float s = 0.0f;
            #pragma unroll
            for (int jc = 0; jc < 6; ++jc) {
                float4 g = g4[jc], ww = w4[jc];
                s += g.x * ww.x; s += g.y * ww.y; s += g.z * ww.z; s += g.w * ww.w;
            }
            sT[k * APAD + n] = s;
        }
        lds_barrier();

        // P5: v[i*21+k] = b2[k] + A[i,:] . h2T[k,:]
        if (t < 441) {
            int r = t / 21, k = t - r * 21;
            const float4* a4 = (const float4*)&sA[r * APAD];
            const float4* h4 = (const float4*)&sT[k * APAD];
            float s = sb2[k];
            #pragma unroll
            for (int jc = 0; jc < 6; ++jc) {
                float4 a = a4[jc], h = h4[jc];
                s += a.x * h.x; s += a.y * h.y; s += a.z * h.z; s += a.w * h.w;
            }
            sv[t] = s;
        }
        lds_barrier();

        // zero-ready gate (block 63 set g_zr ~4µs ago; ~one poll)
        if (t == 0) {
            while (flag_load(&g_zr) == 0u) __builtin_amdgcn_s_sleep(1);
        }
        __syncthreads();

        // FC1 (row-split): rows [21b, 21b+21)
        {
            float s = 0.0f;
            #pragma unroll
            for (int r = 0; r < 21; ++r) s += sv[21 * b + r] * wf1v[r];
            agent_fadd(&ws[WS_ACC1 + t], s);
        }
    }

    grid_barrier(b, 1);   // acc1 complete (and acc2/acc3 zeros via block 63)

    // ---------------- FC2: blocks 21..36, rows [32(b-21), +32) -------------
    if (do_fc2) {
        if (t < 32)
            x1s[t] = fmaxf(agent_load(&ws[WS_ACC1 + 32 * (b - 21) + t]) + rbf1, 0.0f);
        lds_barrier();
        float s = 0.0f;
        #pragma unroll
        for (int j = 0; j < 32; ++j) s += x1s[j] * wf2v[j];
        agent_fadd(&ws[WS_ACC2 + t], s);
    }

    grid_barrier(b, 2);   // acc2 complete

    // ---------------- FC3: blocks 37..44, rows [64(b-37), +64) -------------
    if (do_fc3) {
        if (t < 64)
            x2s[t] = fmaxf(agent_load(&ws[WS_ACC2 + 64 * (b - 37) + t]) + rbf2, 0.0f);
        lds_barrier();
        if (t < 256) {
            float s = 0.0f;
            #pragma unroll
            for (int j = 0; j < 64; ++j) s += x2s[j] * wf3v[j];
            agent_fadd(&ws[WS_ACC3 + t], s);
        }
    }

    // ---------------- finale: completion count; 64th block finalizes -------
    __syncthreads();                        // drain this block's FC3 adds
    if (t == 0) {
        unsigned prev = __hip_atomic_fetch_add(&g_cnt, 1u, __ATOMIC_RELAXED,
                                               __HIP_MEMORY_SCOPE_AGENT);
        sflag = (prev == 63u) ? 1u : 0u;
    }
    __syncthreads();
    if (sflag) {
        if (t < 256) {
            float a = agent_load(&ws[WS_ACC3 + t]) + rbf3;
            out[t] = fmaxf(a, 0.0f);
        }
        // Restore ALL sync words to 0 for the next launch. Every use of these
        // words in this launch happens-before the 64th g_cnt increment, and
        // the end-of-dispatch release publishes the resets before the next
        // kernel on this stream can start.
        if (t >= 256 && t < 320) flag_store(&g_arrive[(t - 256) * 16], 0u);
        if (t == 320) flag_store(&g_go, 0u);
        if (t == 321) flag_store(&g_zr, 0u);
        if (t == 322) flag_store(&g_cnt, 0u);
    }
}

extern "C" void kernel_launch(void* const* d_in, const int* in_sizes, int n_in,
                              void* d_out, int out_size, void* d_ws, size_t ws_size,
                              hipStream_t stream)
{
    const float* state      = (const float*)d_in[0];
    const int*   edge_index = (const int*)  d_in[1];
    const float* W1  = (const float*)d_in[2];
    const float* b1  = (const float*)d_in[3];
    const float* W2  = (const float*)d_in[4];
    const float* b2  = (const float*)d_in[5];
    const float* Wf1 = (const float*)d_in[6];
    const float* bf1 = (const float*)d_in[7];
    const float* Wf2 = (const float*)d_in[8];
    const float* bf2 = (const float*)d_in[9];
    const float* Wf3 = (const float*)d_in[10];
    const float* bf3 = (const float*)d_in[11];

    float* ws  = (float*)d_ws;
    float* out = (float*)d_out;

    fused_kernel<<<64, 512, 0, stream>>>(state, edge_index, W1, b1, W2, b2,
                                         Wf1, bf1, Wf2, bf2, Wf3, bf3, ws, out);
}

// Round 15
// 15.487 us; speedup vs baseline: 2.1518x; 1.0632x over previous
//
#include <hip/hip_runtime.h>
#include <math.h>

#define APAD 28          // padded row stride for 21-wide tiles
#define W1PAD 132        // padded row stride for 128-wide tiles

// ws float layout (acc zeroed by block 63 each launch; poison-safe):
#define WS_ACC1 0
#define WS_ACC2 512
#define WS_ACC3 1024

// Reset-based sync state: all words are 0 at module load, and the finalizer
// block restores every word to 0 before kernel end (stream ordering + the
// end-of-dispatch release fence make this visible to the next launch).
__device__ unsigned g_arrive[64 * 16];   // 64B-strided arrival slots
__device__ unsigned g_go;                // barrier release word
__device__ unsigned g_zr;                // accumulators-zeroed flag
__device__ unsigned g_cnt;               // finale completion counter

// Agent-scope relaxed atomics: cache-bypassing ops served at the coherence
// point -> no L2 wb/inv fences needed anywhere.
__device__ __forceinline__ float agent_load(const float* p) {
    return __hip_atomic_load(p, __ATOMIC_RELAXED, __HIP_MEMORY_SCOPE_AGENT);
}
__device__ __forceinline__ void agent_store(float* p, float v) {
    __hip_atomic_store(p, v, __ATOMIC_RELAXED, __HIP_MEMORY_SCOPE_AGENT);
}
__device__ __forceinline__ unsigned flag_load(const unsigned* p) {
    return __hip_atomic_load(p, __ATOMIC_RELAXED, __HIP_MEMORY_SCOPE_AGENT);
}
__device__ __forceinline__ void flag_store(unsigned* p, unsigned v) {
    __hip_atomic_store(p, v, __ATOMIC_RELAXED, __HIP_MEMORY_SCOPE_AGENT);
}
__device__ __forceinline__ float agent_fadd(float* p, float v) {
    return __hip_atomic_fetch_add(p, v, __ATOMIC_RELAXED, __HIP_MEMORY_SCOPE_AGENT);
}

// Block barrier waiting ONLY on LDS ops (lgkmcnt): global prefetch loads
// stay in flight across it (__syncthreads would drain vmcnt(0)).
__device__ __forceinline__ void lds_barrier() {
    asm volatile("s_waitcnt lgkmcnt(0)\n\ts_barrier" ::: "memory");
}

// Hierarchical grid barrier with an OFF-CRITICAL-PATH leader (block 62,
// otherwise idle): it polls arrivals while workers still compute and
// releases immediately when the last worker arrives. Entry __syncthreads
// drains this block's stores/atomics (vmcnt 0) before the arrival flag.
#define BAR_LEADER 62
__device__ __forceinline__ void grid_barrier(int blk, unsigned phase) {
    __syncthreads();
    if (blk == BAR_LEADER) {
        if (threadIdx.x < 64 && threadIdx.x != BAR_LEADER) {
            while (flag_load(&g_arrive[threadIdx.x * 16]) < phase)
                __builtin_amdgcn_s_sleep(1);
        }
        __syncthreads();   // all lanes saw their arrival
        if (threadIdx.x == 0) flag_store(&g_go, phase);
    } else {
        if (threadIdx.x == 0) {
            flag_store(&g_arrive[blk * 16], phase);
            while (flag_load(&g_go) < phase)
                __builtin_amdgcn_s_sleep(1);
        }
    }
    __syncthreads();
}

// Single launch, 64 blocks x 512 threads, role-split:
//   blocks 0-20 : GCN (own row) + FC1 rows [21b, 21b+21)   (fan-in 21)
//   blocks 21-36: FC2 rows [32(b-21), +32)                 (fan-in 16)
//   blocks 37-44: FC3 rows [64(b-37), +64)                 (fan-in 8)
//   block 62    : barrier leader (idle otherwise; polls off-critical-path)
//   block 63    : zeroes acc1/acc2/acc3, sets g_zr
// Barriers: FC1 -> bar(1) -> FC2 -> bar(2) -> FC3 -> completion-count finale.
// The g_zr gate is folded INTO the P5 phase (lane 448 polls while 21 threads
// compute v) -> one lds_barrier covers both, removing 2 syncs vs round 14.
__global__ __launch_bounds__(512) void fused_kernel(
    const float* __restrict__ state,      // [B,21,128], only batch 0 used
    const int*   __restrict__ edge_index, // [2,128]
    const float* __restrict__ W1,         // [128,21]
    const float* __restrict__ b1,         // [21]
    const float* __restrict__ W2,         // [21,21]
    const float* __restrict__ b2,         // [21]
    const float* __restrict__ Wf1,        // [441,512]
    const float* __restrict__ bf1,        // [512]
    const float* __restrict__ Wf2,        // [512,512]
    const float* __restrict__ bf2,        // [512]
    const float* __restrict__ Wf3,        // [512,256]
    const float* __restrict__ bf3,        // [256]
    float* __restrict__ ws,
    float* __restrict__ out)
{
    const int b = blockIdx.x;
    const int t = threadIdx.x;

    const bool is_gcn = (b < 21);                 // also the FC1 blocks
    const bool do_fc2 = (b >= 21 && b < 37);
    const bool do_fc3 = (b >= 37 && b < 45);

    // ---------------- LDS ----------------
    __shared__ float sA[21 * APAD];
    __shared__ float sX[21 * W1PAD];
    __shared__ float sW1T[21 * W1PAD];
    __shared__ float sW2T[21 * APAD];
    __shared__ float sT[21 * APAD];      // h1T then h2T
    __shared__ float sG[21 * APAD];      // g1
    __shared__ float sv[441];
    __shared__ float sdeg[21];
    __shared__ float sb1[21], sb2[21];
    __shared__ float x1s[32], x2s[64];
    __shared__ unsigned sflag;

    // ---------------- role prefetches (coalesced row reads) ----------------
    float wf1v[21];
    if (is_gcn) {
        #pragma unroll
        for (int i = 0; i < 21; ++i) wf1v[i] = Wf1[(size_t)(21 * b + i) * 512 + t];
    }
    float wf2v[32];
    float rbf1 = 0.0f;
    if (do_fc2) {
        #pragma unroll
        for (int i = 0; i < 32; ++i) wf2v[i] = Wf2[(size_t)(32 * (b - 21) + i) * 512 + t];
        if (t < 32) rbf1 = bf1[32 * (b - 21) + t];
    }
    float wf3v[64];
    float rbf2 = 0.0f;
    if (do_fc3) {
        if (t < 256) {
            #pragma unroll
            for (int i = 0; i < 64; ++i) wf3v[i] = Wf3[(size_t)(64 * (b - 37) + i) * 256 + t];
        }
        if (t < 64) rbf2 = bf2[64 * (b - 37) + t];
    }
    const float rbf3 = bf3[t & 255];   // any block may finalize

    // ---------------- zeroer: block 63 ----------------
    if (b == 63) {
        agent_store(&ws[WS_ACC1 + t], 0.0f);
        agent_store(&ws[WS_ACC2 + t], 0.0f);
        if (t < 256) agent_store(&ws[WS_ACC3 + t], 0.0f);
        __syncthreads();                          // drain zero stores (vmcnt 0)
        if (t == 0) flag_store(&g_zr, 1u);        // zeros globally visible
    }

    // ---------------- GCN: blocks 0..20 only ----------------
    if (is_gcn) {
        // P0: zero pads, stage X/W1T/W2T, edges
        for (int i = t; i < 21 * APAD; i += 512) {
            sA[i] = 0.0f; sW2T[i] = 0.0f; sT[i] = 0.0f; sG[i] = 0.0f;
        }
        if (t < 21) { sdeg[t] = 1.0f; sb1[t] = b1[t]; sb2[t] = b2[t]; }
        {
            const float4* src4 = (const float4*)state;      // batch 0
            for (int i = t; i < 672; i += 512) {            // 21*128/4
                int n = i >> 5, fc = i & 31;
                ((float4*)&sX[n * W1PAD])[fc] = src4[i];
            }
        }
        for (int i = t; i < 2688; i += 512) {               // W1 -> sW1T[k][f]
            int f = i / 21, k = i - f * 21;
            sW1T[k * W1PAD + f] = W1[i];
        }
        for (int i = t; i < 441; i += 512) {                // W2 -> sW2T[k][f]
            int f = i / 21, k = i - f * 21;
            sW2T[k * APAD + f] = W2[i];
        }
        int er = 0, ec = 0;
        if (t < 128) { er = edge_index[t]; ec = edge_index[128 + t]; }
        lds_barrier();

        // P1: adjacency scatter (+deg, +self-loop)  ||  h1 = X @ W1
        if (t < 128) {
            atomicAdd(&sA[er * APAD + ec], 1.0f);
            atomicAdd(&sdeg[ec], 1.0f);
        }
        if (t < 21) atomicAdd(&sA[t * APAD + t], 1.0f);
        if (t < 441) {
            int n = t / 21, k = t - n * 21;
            const float4* x4 = (const float4*)&sX[n * W1PAD];
            const float4* w4 = (const float4*)&sW1T[k * W1PAD];
            float s = 0.0f;
            #pragma unroll
            for (int fc = 0; fc < 32; ++fc) {
                float4 a = x4[fc], ww = w4[fc];
                s += a.x * ww.x; s += a.y * ww.y; s += a.z * ww.z; s += a.w * ww.w;
            }
            sT[k * APAD + n] = s;
        }
        lds_barrier();

        // P2: normalize A
        if (t < 441) {
            int r = t / 21, c = t - r * 21;
            float dr = 1.0f / sqrtf(sdeg[r]);
            float dc = 1.0f / sqrtf(sdeg[c]);
            sA[r * APAD + c] = dr * sA[r * APAD + c] * dc;
        }
        lds_barrier();

        // P3: g1[i,k] = b1[k] + A[i,:] . h1T[k,:]
        if (t < 441) {
            int r = t / 21, k = t - r * 21;
            const float4* a4 = (const float4*)&sA[r * APAD];
            const float4* h4 = (const float4*)&sT[k * APAD];
            float s = sb1[k];
            #pragma unroll
            for (int jc = 0; jc < 6; ++jc) {
                float4 a = a4[jc], h = h4[jc];
                s += a.x * h.x; s += a.y * h.y; s += a.z * h.z; s += a.w * h.w;
            }
            sG[r * APAD + k] = s;
        }
        lds_barrier();

        // P4: h2[n,k] = g1[n,:] . W2T[k,:]
        if (t < 441) {
            int n = t / 21, k = t - n * 21;
            const float4* g4 = (const float4*)&sG[n * APAD];
            const float4* w4 = (const float4*)&sW2T[k * APAD];
            float s = 0.0f;
            #pragma unroll
            for (int jc = 0; jc < 6; ++jc) {
                float4 g = g4[jc], ww = w4[jc];
                s += g.x * ww.x; s += g.y * ww.y; s += g.z * ww.z; s += g.w * ww.w;
            }
            sT[k * APAD + n] = s;
        }
        lds_barrier();

        // P5: v[i*21+k] = b2[k] + A[i,:] . h2T[k,:]
        // Gate folded in: lane 448 (idle during P5) polls g_zr concurrently;
        // the single lds_barrier below orders BOTH sv writes and the gate
        // before the FC1 adds (zero serial sync cost).
        if (t < 441) {
            int r = t / 21, k = t - r * 21;
            const float4* a4 = (const float4*)&sA[r * APAD];
            const float4* h4 = (const float4*)&sT[k * APAD];
            float s = sb2[k];
            #pragma unroll
            for (int jc = 0; jc < 6; ++jc) {
                float4 a = a4[jc], h = h4[jc];
                s += a.x * h.x; s += a.y * h.y; s += a.z * h.z; s += a.w * h.w;
            }
            sv[t] = s;
        }
        if (t == 448) {
            while (flag_load(&g_zr) == 0u) __builtin_amdgcn_s_sleep(1);
        }
        lds_barrier();

        // FC1 (row-split): rows [21b, 21b+21)
        {
            float s = 0.0f;
            #pragma unroll
            for (int r = 0; r < 21; ++r) s += sv[21 * b + r] * wf1v[r];
            agent_fadd(&ws[WS_ACC1 + t], s);
        }
    }

    grid_barrier(b, 1);   // acc1 complete (and acc2/acc3 zeros via block 63)

    // ---------------- FC2: blocks 21..36, rows [32(b-21), +32) -------------
    if (do_fc2) {
        if (t < 32)
            x1s[t] = fmaxf(agent_load(&ws[WS_ACC1 + 32 * (b - 21) + t]) + rbf1, 0.0f);
        lds_barrier();
        float s = 0.0f;
        #pragma unroll
        for (int j = 0; j < 32; ++j) s += x1s[j] * wf2v[j];
        agent_fadd(&ws[WS_ACC2 + t], s);
    }

    grid_barrier(b, 2);   // acc2 complete

    // ---------------- FC3: blocks 37..44, rows [64(b-37), +64) -------------
    if (do_fc3) {
        if (t < 64)
            x2s[t] = fmaxf(agent_load(&ws[WS_ACC2 + 64 * (b - 37) + t]) + rbf2, 0.0f);
        lds_barrier();
        if (t < 256) {
            float s = 0.0f;
            #pragma unroll
            for (int j = 0; j < 64; ++j) s += x2s[j] * wf3v[j];
            agent_fadd(&ws[WS_ACC3 + t], s);
        }
    }

    // ---------------- finale: completion count; 64th block finalizes -------
    __syncthreads();                        // drain this block's FC3 adds
    if (t == 0) {
        unsigned prev = __hip_atomic_fetch_add(&g_cnt, 1u, __ATOMIC_RELAXED,
                                               __HIP_MEMORY_SCOPE_AGENT);
        sflag = (prev == 63u) ? 1u : 0u;
    }
    __syncthreads();
    if (sflag) {
        if (t < 256) {
            float a = agent_load(&ws[WS_ACC3 + t]) + rbf3;
            out[t] = fmaxf(a, 0.0f);
        }
        // Restore ALL sync words to 0 for the next launch (all uses in this
        // launch happen-before the 64th g_cnt increment; end-of-dispatch
        // release publishes the resets before the next launch starts).
        if (t >= 256 && t < 320) flag_store(&g_arrive[(t - 256) * 16], 0u);
        if (t == 320) flag_store(&g_go, 0u);
        if (t == 321) flag_store(&g_zr, 0u);
        if (t == 322) flag_store(&g_cnt, 0u);
    }
}

extern "C" void kernel_launch(void* const* d_in, const int* in_sizes, int n_in,
                              void* d_out, int out_size, void* d_ws, size_t ws_size,
                              hipStream_t stream)
{
    const float* state      = (const float*)d_in[0];
    const int*   edge_index = (const int*)  d_in[1];
    const float* W1  = (const float*)d_in[2];
    const float* b1  = (const float*)d_in[3];
    const float* W2  = (const float*)d_in[4];
    const float* b2  = (const float*)d_in[5];
    const float* Wf1 = (const float*)d_in[6];
    const float* bf1 = (const float*)d_in[7];
    const float* Wf2 = (const float*)d_in[8];
    const float* bf2 = (const float*)d_in[9];
    const float* Wf3 = (const float*)d_in[10];
    const float* bf3 = (const float*)d_in[11];

    float* ws  = (float*)d_ws;
    float* out = (float*)d_out;

    fused_kernel<<<64, 512, 0, stream>>>(state, edge_index, W1, b1, W2, b2,
                                         Wf1, bf1, Wf2, bf2, Wf3, bf3, ws, out);
}